// Round 10
// baseline (196.654 us; speedup 1.0000x reference)
//
#include <hip/hip_runtime.h>
#include <math.h>

#define B_ 8
#define N_ 1024
#define M_ 20000
#define C_ 80
#define G_ 64
typedef unsigned long long ull;

__device__ __forceinline__ float iou1(float ax, float ay, float az, float aw,
                                      float bx, float by, float bz, float bw) {
    // legacy +1 convention, exact reference arithmetic order
    float lx = fmaxf(ax, bx), ly = fmaxf(ay, by);
    float rx = fminf(az, bz), ry = fminf(aw, bw);
    float w = fmaxf(rx - lx + 1.0f, 0.0f), h = fmaxf(ry - ly + 1.0f, 0.0f);
    float ov = w * h;
    float a1 = (az - ax + 1.0f) * (aw - ay + 1.0f);
    float a2 = (bz - bx + 1.0f) * (bw - by + 1.0f);
    return ov / (a1 + a2 - ov);
}

// ---- Fully fused: sort + in-register adjacency + chunk-phase sweep + loss ----
// One block per batch, 1024 threads; thread t == sorted position t.
__global__ __launch_bounds__(1024) void nms_fused_kernel(
    const int* __restrict__ pos_inds, const int* __restrict__ pos_gt,
    const float* __restrict__ gt_bboxes, const float* __restrict__ bbox_preds,
    const float* __restrict__ cls_scores, const int* __restrict__ gt_labels,
    float* __restrict__ out) {
    const int b = blockIdx.x, t = threadIdx.x;
    const int wtop = t >> 6, lane = t & 63;

    __shared__ ull s_keys[N_];             //  8 KB (sort scratch)
    __shared__ float4 s_box[N_];           // 16 KB (sorted boxes)
    __shared__ float s_area[N_];           //  4 KB
    __shared__ float s_score[N_];          //  4 KB
    __shared__ short s_g[N_];              //  2 KB
    __shared__ ull s_S[16];                // survivor bitmask
    __shared__ unsigned short s_step[N_];  //  2 KB: position -> rank
    __shared__ unsigned short s_surv[N_];  //  2 KB: rank -> position
    __shared__ float s_ts[N_];             //  4 KB: per-step push sums
    __shared__ int s_cnt[N_], s_kills[N_]; //  8 KB
    __shared__ int s_first[G_];
    __shared__ int s_wpre[17];
    __shared__ float s_tpull, s_tpush;
    __shared__ int s_pcnt, s_qcnt;
    // ~51 KB total

    // --- init + sort keys: descending score, tie -> ascending original index ---
    s_ts[t] = 0.f; s_cnt[t] = 0; s_kills[t] = 0; s_step[t] = 0xffff;
    if (t < 16) s_S[t] = 0ull;
    if (t < G_) s_first[t] = 0x7fffffff;
    if (t == 0) { s_tpull = 0.f; s_tpush = 0.f; s_pcnt = 0; s_qcnt = 0; }

    ull key;
    {
        int g0 = pos_gt[b * N_ + t];
        int lab = gt_labels[b * G_ + g0];
        int pi = pos_inds[b * N_ + t];
        float s = cls_scores[(size_t)b * (M_ * C_) + (size_t)pi * C_ + lab];
        key = ((ull)(~__float_as_uint(s)) << 32) | (unsigned)t;
    }
    __syncthreads();

    // --- bitonic sort (R9-proven): registers intra-wave, LDS for jj>=64 ---
    for (unsigned k2 = 2; k2 <= N_; k2 <<= 1) {
        for (unsigned jj = k2 >> 1; jj; jj >>= 1) {
            ull other;
            if (jj >= 64) {
                s_keys[t] = key; __syncthreads();
                other = s_keys[t ^ jj]; __syncthreads();
            } else {
                int lo = __shfl_xor((int)(unsigned)key, (int)jj);
                int hi = __shfl_xor((int)(unsigned)(key >> 32), (int)jj);
                other = ((ull)(unsigned)hi << 32) | (unsigned)lo;
            }
            bool keep_min = (((t & jj) == 0) == ((t & k2) == 0));
            ull mn = key < other ? key : other;
            ull mx = key < other ? other : key;
            key = keep_min ? mn : mx;
        }
    }

    // --- stage sorted elements in LDS (same values R9's elemG carried) ---
    {
        int j = (int)(unsigned)(key & 0xFFFFFFFFull);
        float ss = __uint_as_float(~(unsigned)(key >> 32));   // exact score recovery
        const float* bp = bbox_preds + (size_t)(b * N_ + j) * 4;
        float x0 = bp[0], y0 = bp[1], x1 = bp[2], y1 = bp[3];
        s_box[t] = make_float4(x0, y0, x1, y1);
        s_area[t] = (x1 - x0 + 1.0f) * (y1 - y0 + 1.0f);
        s_score[t] = ss;
        s_g[t] = (short)pos_gt[b * N_ + j];
    }
    __syncthreads();

    // --- adjacency words into registers: bit u of rw[w] = (iou(t, 64w+u) > 0.5) ---
    // Identical FP expression/order as R9's adj_kernel => identical bits.
    // Words needed: w < wtop (full) and w == wtop (full, in-chunk both directions).
    ull rw[16];
    {
        float4 me = s_box[t];
        float a1 = s_area[t];
        float ax0 = me.x, ay0 = me.y, az1 = me.z + 1.0f, aw1 = me.w + 1.0f;
#pragma unroll
        for (int w = 0; w < 16; ++w) {
            ull bits = 0ull;
            if (w <= wtop) {          // wave-uniform condition
                int qbase = w << 6;
                for (int u = 0; u < 64; ++u) {   // s_box[qbase+u]: wave-wide broadcast read
                    float4 o = s_box[qbase + u];
                    float lx = fmaxf(ax0, o.x), ly = fmaxf(ay0, o.y);
                    float rx = fminf(az1, o.z + 1.0f), ry = fminf(aw1, o.w + 1.0f);
                    float ww = fmaxf(rx - lx, 0.0f), hh = fmaxf(ry - ly, 0.0f);
                    float I = ww * hh;
                    bits |= (3.0f * I > a1 + s_area[qbase + u]) ? (1ull << u) : 0ull;
                }
            }
            rw[w] = bits;
        }
    }
    __syncthreads();

    // ---- sweep: 16 ordered chunk phases (R9-proven batched-round acceptance) ----
    bool alive_f = true;
#pragma unroll
    for (int c = 0; c < 16; ++c) {
        if (wtop == c) {   // wave-uniform; whole wave active
            ull alive = __ballot(alive_f);
            ull Sc = 0ull;
            const ull below = (1ull << lane) - 1ull;     // lane 0 -> 0
            const ull myearly = rw[c] & below;           // earlier in-chunk neighbors
            while (alive) {
                bool inU = ((alive >> lane) & 1ull) && ((myearly & alive) == 0ull);
                ull U = __ballot(inU);
                unsigned klo = inU ? (unsigned)rw[c] : 0u;
                unsigned khi = inU ? (unsigned)(rw[c] >> 32) : 0u;
#pragma unroll
                for (int off = 32; off; off >>= 1) {   // OR-reduce kill rows of U
                    klo |= (unsigned)__shfl_xor((int)klo, off);
                    khi |= (unsigned)__shfl_xor((int)khi, off);
                }
                ull kills = ((ull)khi << 32) | klo;
                Sc |= U;
                alive &= ~U;
                alive &= ~kills;
            }
            if (lane == 0) s_S[c] = Sc;
        }
        __syncthreads();
        if (wtop > c && alive_f && (rw[c] & s_S[c]) != 0ull) alive_f = false;
    }

    // ---- survivor ranks (pop order = ascending position, proven monotone) ----
    if (t < 16) s_wpre[t + 1] = __popcll(s_S[t]);
    __syncthreads();
    if (t == 0) { s_wpre[0] = 0; for (int w = 0; w < 16; ++w) s_wpre[w + 1] += s_wpre[w]; }
    __syncthreads();
    const int K = s_wpre[16];
    const ull sbit = 1ull << lane;
    const bool isS = (s_S[wtop] & sbit) != 0ull;
    int myrank = -1;
    if (isS) {
        myrank = s_wpre[wtop] + __popcll(s_S[wtop] & (sbit - 1ull));
        s_step[t] = (unsigned short)myrank;
        s_surv[myrank] = (unsigned short)t;
        atomicMin(&s_first[(int)s_g[t]], myrank);
    }
    __syncthreads();

    // ---- suppressed j: killer = first adjacent survivor below j ----
    if (!isS) {
        int kp = -1;
#pragma unroll
        for (int w = 15; w >= 0; --w) {   // descending so final = lowest word hit
            ull m = rw[w] & s_S[w];       // rw[w]=0 for w>wtop
            if (w == wtop) m &= (1ull << lane) - 1ull;
            if (m) kp = (w << 6) + (int)(__ffsll(m) - 1);
        }
        if (kp >= 0) {   // always true: every non-survivor has a killer
            int q = s_step[kp];
            atomicAdd(&s_kills[q], 1);   // 'remaining' evidence
            int gq = (int)s_g[kp], gj = (int)s_g[t];
            if (gq != gj) {
                float4 qa = s_box[kp], ja = s_box[t];
                float ov = iou1(qa.x, qa.y, qa.z, qa.w, ja.x, ja.y, ja.z, ja.w);
                const float* gbq = gt_bboxes + (size_t)(b * G_ + gq) * 4;
                const float* gbj = gt_bboxes + (size_t)(b * G_ + gj) * 4;
                float gov = iou1(gbq[0], gbq[1], gbq[2], gbq[3],
                                 gbj[0], gbj[1], gbj[2], gbj[3]);
                if (ov > gov) {
                    atomicAdd(&s_cnt[q], 1);
                    atomicAdd(&s_ts[q], -__logf(1.0f - ov) * s_score[t]);
                }
            }
        }
    }
    __syncthreads();

    // ---- pull per survivor + per-step push normalization ----
    if (isS) {
        int k = myrank, g = (int)s_g[t], f = s_first[g];
        if (f < k) {
            atomicAdd(&s_pcnt, 1);   // NOT gated on remaining (matches reference)
            // pull dropped iff last pop and it kills nobody (remaining == false)
            bool drop = (k == K - 1) && (s_kills[k] == 0);
            if (!drop) {
                float4 fA = s_box[s_surv[f]], kA = s_box[t];
                float ov = iou1(fA.x, fA.y, fA.z, fA.w, kA.x, kA.y, kA.z, kA.w);
                atomicAdd(&s_tpull, -__logf(0.5f + fmaxf(ov, 1e-6f)) * s_score[t]);
            }
        }
        if (s_cnt[k] > 0) {   // cnt>0 => kills>0 => remaining true
            atomicAdd(&s_tpush, s_ts[k] / (float)s_cnt[k]);
            atomicAdd(&s_qcnt, s_cnt[k]);
        }
    }
    __syncthreads();

    if (t == 0) {
        atomicAdd(&out[0], (s_tpush / ((float)s_qcnt + 1e-6f)) * 0.125f);  // mean push, B=8
        atomicAdd(&out[1], (s_tpull / ((float)s_pcnt + 1e-6f)) * 0.125f);  // mean pull
    }
}

extern "C" void kernel_launch(void* const* d_in, const int* in_sizes, int n_in,
                              void* d_out, int out_size, void* d_ws, size_t ws_size,
                              hipStream_t stream) {
    const int* pos_inds = (const int*)d_in[0];
    const int* pos_gt = (const int*)d_in[1];
    const float* gt_bboxes = (const float*)d_in[2];
    const float* bbox_preds = (const float*)d_in[3];
    const float* cls_scores = (const float*)d_in[4];
    const int* gt_labels = (const int*)d_in[5];
    float* out = (float*)d_out;

    hipMemsetAsync(out, 0, 2 * sizeof(float), stream);  // d_out re-poisoned 0xAA each call
    nms_fused_kernel<<<dim3(B_), dim3(1024), 0, stream>>>(
        pos_inds, pos_gt, gt_bboxes, bbox_preds, cls_scores, gt_labels, out);
}

// Round 11
// 134.675 us; speedup vs baseline: 1.4602x; 1.4602x over previous
//
#include <hip/hip_runtime.h>
#include <math.h>

#define B_ 8
#define N_ 1024
#define M_ 20000
#define C_ 80
#define G_ 64
typedef unsigned long long ull;

// ws: elem [B][1024][2]float4 (256KB) | adj [B][1024][64]u16 (1MB)
#define WS_ELEM_OFF 0
#define WS_ADJ_OFF  262144

__device__ __forceinline__ float iou1(float ax, float ay, float az, float aw,
                                      float bx, float by, float bz, float bw) {
    // legacy +1 convention, exact reference arithmetic order
    float lx = fmaxf(ax, bx), ly = fmaxf(ay, by);
    float rx = fminf(az, bz), ry = fminf(aw, bw);
    float w = fmaxf(rx - lx + 1.0f, 0.0f), h = fmaxf(ry - ly + 1.0f, 0.0f);
    float ov = w * h;
    float a1 = (az - ax + 1.0f) * (aw - ay + 1.0f);
    float a2 = (bz - bx + 1.0f) * (bw - by + 1.0f);
    return ov / (a1 + a2 - ov);
}

// ---- K1: scores + hybrid bitonic sort (double-buffered LDS stages) + table ----
__global__ __launch_bounds__(1024) void prep_kernel(
    const int* __restrict__ pos_inds, const int* __restrict__ pos_gt,
    const float* __restrict__ bbox_preds, const float* __restrict__ cls_scores,
    const int* __restrict__ gt_labels, float4* __restrict__ elemG,
    float* __restrict__ out) {
    const int b = blockIdx.x, t = threadIdx.x;
    __shared__ ull s_k2[2][N_];   // 16 KB: A/B buffers -> 1 barrier per LDS stage

    if (b == 0 && t == 0) { out[0] = 0.f; out[1] = 0.f; }  // init before sweep_loss

    int g0 = pos_gt[b * N_ + t];
    int lab = gt_labels[b * G_ + g0];
    int pi = pos_inds[b * N_ + t];
    float s = cls_scores[(size_t)b * (M_ * C_) + (size_t)pi * C_ + lab];
    // descending score, tie -> ascending original index (jnp.argmax tie-break)
    ull key = ((ull)(~__float_as_uint(s)) << 32) | (unsigned)t;

    int pb = 0;
    for (unsigned k2 = 2; k2 <= N_; k2 <<= 1) {
        for (unsigned jj = k2 >> 1; jj; jj >>= 1) {
            ull other;
            if (jj >= 64) {   // cross-wave: alternating buffers, single barrier
                s_k2[pb][t] = key;
                __syncthreads();
                other = s_k2[pb][t ^ jj];
                pb ^= 1;
            } else {          // intra-wave: register shfl, no barrier
                int lo = __shfl_xor((int)(unsigned)key, (int)jj);
                int hi = __shfl_xor((int)(unsigned)(key >> 32), (int)jj);
                other = ((ull)(unsigned)hi << 32) | (unsigned)lo;
            }
            bool keep_min = (((t & jj) == 0) == ((t & k2) == 0));
            ull mn = key < other ? key : other;
            ull mx = key < other ? other : key;
            key = keep_min ? mn : mx;
        }
    }

    int j = (int)(unsigned)(key & 0xFFFFFFFFull);
    float ss = __uint_as_float(~(unsigned)(key >> 32));   // exact score recovery
    const float* bp = bbox_preds + (size_t)(b * N_ + j) * 4;
    float x0 = bp[0], y0 = bp[1], x1 = bp[2], y1 = bp[3];
    int g = pos_gt[b * N_ + j];
    float area = (x1 - x0 + 1.0f) * (y1 - y0 + 1.0f);
    elemG[(size_t)(b * N_ + t) * 2 + 0] = make_float4(x0, y0, x1, y1);
    elemG[(size_t)(b * N_ + t) * 2 + 1] = make_float4(__int_as_float(g), ss, area, 0.f);
}

// ---- K2: TRIANGULAR adjacency: only words w <= r>>6 are ever read downstream ----
__global__ __launch_bounds__(256) void adj_kernel(
    const float4* __restrict__ elemG, unsigned short* __restrict__ adjG) {
    const int b = blockIdx.y;
    const int r = blockIdx.x * 4 + (threadIdx.x >> 6);
    const int lane = threadIdx.x & 63;
    if ((lane >> 2) > (r >> 6)) return;   // this u16 lies in a 64-bit word w > r>>6: never read
    float4 rA = elemG[(size_t)(b * N_ + r) * 2];
    float ax0 = rA.x, ay0 = rA.y;
    float az1 = rA.z + 1.0f, aw1 = rA.w + 1.0f;
    float a1 = (rA.z - rA.x + 1.0f) * (rA.w - rA.y + 1.0f);
    unsigned bits = 0;
#pragma unroll
    for (int u = 0; u < 16; ++u) {
        int cpos = lane * 16 + u;
        float4 cA = elemG[(size_t)(b * N_ + cpos) * 2];
        float lx = fmaxf(ax0, cA.x), ly = fmaxf(ay0, cA.y);
        float rx = fminf(az1, cA.z + 1.0f), ry = fminf(aw1, cA.w + 1.0f);
        float w = fmaxf(rx - lx, 0.0f), h = fmaxf(ry - ly, 0.0f);
        float I = w * h;
        float a2 = (cA.z - cA.x + 1.0f) * (cA.w - cA.y + 1.0f);
        bits |= (3.0f * I > a1 + a2) ? (1u << u) : 0u;   // iou>0.5 <=> 3I > a1+a2
    }
    adjG[(size_t)(b * N_ + r) * 64 + lane] = (unsigned short)bits;
}

// ---- K3 (R9 verbatim): fused sweep (batched-round chunk acceptance) + loss ----
__global__ __launch_bounds__(1024) void sweep_loss_kernel(
    const float4* __restrict__ elemG, const unsigned short* __restrict__ adjG,
    const float* __restrict__ gt_bboxes, float* __restrict__ out) {
    const int b = blockIdx.x, t = threadIdx.x;
    const int wtop = t >> 6, lane = t & 63;

    __shared__ float4 s_box[N_];           // 16 KB
    __shared__ float s_score[N_];          // 4 KB
    __shared__ short s_g[N_];              // 2 KB
    __shared__ ull s_S[16];                // survivor bitmask
    __shared__ unsigned short s_step[N_];  // position -> rank
    __shared__ unsigned short s_surv[N_];  // rank -> position
    __shared__ float s_ts[N_];             // per-step push sums
    __shared__ int s_cnt[N_], s_kills[N_], s_first[G_];
    __shared__ int s_wpre[17];
    __shared__ float s_tpull, s_tpush;
    __shared__ int s_pcnt, s_qcnt;

    {   // stage elements + init
        float4 eA = elemG[(size_t)(b * N_ + t) * 2];
        float4 eB = elemG[(size_t)(b * N_ + t) * 2 + 1];
        s_box[t] = eA; s_score[t] = eB.y; s_g[t] = (short)__float_as_int(eB.x);
    }
    s_ts[t] = 0.f; s_cnt[t] = 0; s_kills[t] = 0; s_step[t] = 0xffff;
    if (t < 16) s_S[t] = 0ull;
    if (t < G_) s_first[t] = 0x7fffffff;
    if (t == 0) { s_tpull = 0.f; s_tpush = 0.f; s_pcnt = 0; s_qcnt = 0; }

    // my adjacency row words for chunks <= mine (bit q of word c = adj(t, 64c+q))
    const ull* rowp = (const ull*)(adjG + (size_t)(b * N_ + t) * 64);
    ull rw[16];
#pragma unroll
    for (int c = 0; c < 16; ++c) rw[c] = (c <= wtop) ? rowp[c] : 0ull;

    __syncthreads();

    // ---- sweep: 16 ordered chunk phases (batched-round acceptance, R9-proven) ----
    bool alive_f = true;
#pragma unroll
    for (int c = 0; c < 16; ++c) {
        if (wtop == c) {   // wave-uniform; whole wave active
            ull alive = __ballot(alive_f);
            ull Sc = 0ull;
            const ull below = (1ull << lane) - 1ull;     // lane 0 -> 0
            const ull myearly = rw[c] & below;           // earlier in-chunk neighbors
            while (alive) {
                bool inU = ((alive >> lane) & 1ull) && ((myearly & alive) == 0ull);
                ull U = __ballot(inU);
                unsigned klo = inU ? (unsigned)rw[c] : 0u;
                unsigned khi = inU ? (unsigned)(rw[c] >> 32) : 0u;
#pragma unroll
                for (int off = 32; off; off >>= 1) {   // OR-reduce kill rows of U
                    klo |= (unsigned)__shfl_xor((int)klo, off);
                    khi |= (unsigned)__shfl_xor((int)khi, off);
                }
                ull kills = ((ull)khi << 32) | klo;
                Sc |= U;
                alive &= ~U;
                alive &= ~kills;
            }
            if (lane == 0) s_S[c] = Sc;
        }
        __syncthreads();
        if (wtop > c && alive_f && (rw[c] & s_S[c]) != 0ull) alive_f = false;
    }

    // ---- survivor ranks (pop order = ascending position, proven monotone) ----
    if (t < 16) s_wpre[t + 1] = __popcll(s_S[t]);
    __syncthreads();
    if (t == 0) { s_wpre[0] = 0; for (int w = 0; w < 16; ++w) s_wpre[w + 1] += s_wpre[w]; }
    __syncthreads();
    const int K = s_wpre[16];
    const ull sbit = 1ull << lane;
    const bool isS = (s_S[wtop] & sbit) != 0ull;
    int myrank = -1;
    if (isS) {
        myrank = s_wpre[wtop] + __popcll(s_S[wtop] & (sbit - 1ull));
        s_step[t] = (unsigned short)myrank;
        s_surv[myrank] = (unsigned short)t;
        atomicMin(&s_first[(int)s_g[t]], myrank);
    }
    __syncthreads();

    // ---- suppressed j: killer = first adjacent survivor below j ----
    if (!isS) {
        int kp = -1;
#pragma unroll
        for (int w = 15; w >= 0; --w) {   // descending so final = lowest word hit
            ull m = rw[w] & s_S[w];       // rw[w]=0 for w>wtop
            if (w == wtop) m &= (1ull << lane) - 1ull;
            if (m) kp = (w << 6) + (int)(__ffsll(m) - 1);
        }
        if (kp >= 0) {   // always true: every non-survivor has a killer
            int q = s_step[kp];
            atomicAdd(&s_kills[q], 1);   // 'remaining' evidence
            int gq = (int)s_g[kp], gj = (int)s_g[t];
            if (gq != gj) {
                float4 qa = s_box[kp], ja = s_box[t];
                float ov = iou1(qa.x, qa.y, qa.z, qa.w, ja.x, ja.y, ja.z, ja.w);
                const float* gbq = gt_bboxes + (size_t)(b * G_ + gq) * 4;
                const float* gbj = gt_bboxes + (size_t)(b * G_ + gj) * 4;
                float gov = iou1(gbq[0], gbq[1], gbq[2], gbq[3],
                                 gbj[0], gbj[1], gbj[2], gbj[3]);
                if (ov > gov) {
                    atomicAdd(&s_cnt[q], 1);
                    atomicAdd(&s_ts[q], -__logf(1.0f - ov) * s_score[t]);
                }
            }
        }
    }
    __syncthreads();

    // ---- pull per survivor + per-step push normalization ----
    if (isS) {
        int k = myrank, g = (int)s_g[t], f = s_first[g];
        if (f < k) {
            atomicAdd(&s_pcnt, 1);   // NOT gated on remaining (matches reference)
            // pull dropped iff last pop and it kills nobody (remaining == false)
            bool drop = (k == K - 1) && (s_kills[k] == 0);
            if (!drop) {
                float4 fA = s_box[s_surv[f]], kA = s_box[t];
                float ov = iou1(fA.x, fA.y, fA.z, fA.w, kA.x, kA.y, kA.z, kA.w);
                atomicAdd(&s_tpull, -__logf(0.5f + fmaxf(ov, 1e-6f)) * s_score[t]);
            }
        }
        if (s_cnt[k] > 0) {   // cnt>0 => kills>0 => remaining true
            atomicAdd(&s_tpush, s_ts[k] / (float)s_cnt[k]);
            atomicAdd(&s_qcnt, s_cnt[k]);
        }
    }
    __syncthreads();

    if (t == 0) {
        atomicAdd(&out[0], (s_tpush / ((float)s_qcnt + 1e-6f)) * 0.125f);  // mean push, B=8
        atomicAdd(&out[1], (s_tpull / ((float)s_pcnt + 1e-6f)) * 0.125f);  // mean pull
    }
}

extern "C" void kernel_launch(void* const* d_in, const int* in_sizes, int n_in,
                              void* d_out, int out_size, void* d_ws, size_t ws_size,
                              hipStream_t stream) {
    const int* pos_inds = (const int*)d_in[0];
    const int* pos_gt = (const int*)d_in[1];
    const float* gt_bboxes = (const float*)d_in[2];
    const float* bbox_preds = (const float*)d_in[3];
    const float* cls_scores = (const float*)d_in[4];
    const int* gt_labels = (const int*)d_in[5];
    float* out = (float*)d_out;

    float4* elemG = (float4*)((char*)d_ws + WS_ELEM_OFF);
    unsigned short* adjG = (unsigned short*)((char*)d_ws + WS_ADJ_OFF);

    // out zero-init folded into prep_kernel (prep fully precedes sweep_loss on stream)
    prep_kernel<<<dim3(B_), dim3(1024), 0, stream>>>(
        pos_inds, pos_gt, bbox_preds, cls_scores, gt_labels, elemG, out);
    adj_kernel<<<dim3(256, B_), dim3(256), 0, stream>>>(elemG, adjG);
    sweep_loss_kernel<<<dim3(B_), dim3(1024), 0, stream>>>(elemG, adjG, gt_bboxes, out);
}